// Round 5
// baseline (391.062 us; speedup 1.0000x reference)
//
#include <hip/hip_runtime.h>
#include <hip/hip_bf16.h>
#include <stdint.h>

#define B_ 8
#define NTOK 7225
#define MTOT (B_*NTOK)      // 57800
#define MROWS 58368         // padded rows for all M-row buffers

typedef unsigned short u16;
typedef u16 u16x8 __attribute__((ext_vector_type(8)));
typedef u16 u16x4 __attribute__((ext_vector_type(4)));
typedef __bf16 bf16x8 __attribute__((ext_vector_type(8)));
typedef float f32x4 __attribute__((ext_vector_type(4)));

__device__ inline float bf2f(u16 u){ union{float f;uint32_t i;}c; c.i=((uint32_t)u)<<16; return c.f; }
__device__ inline u16 f2bf(float f){ union{float f;uint32_t i;}c; c.f=f; uint32_t x=c.i;
                                     return (u16)((x + 0x7fffu + ((x>>16)&1u))>>16); }
// packed f32x2 -> bf16x2 (RNE), S0 -> low half
__device__ inline uint32_t cvt_pk_bf16(float a, float b){
  uint32_t r; asm("v_cvt_pk_bf16_f32 %0, %1, %2" : "=v"(r) : "v"(a), "v"(b)); return r;
}
// fast tanh-gelu: 0.5x(1+tanh t) == x * (1 - 1/(exp(2t)+1))
__device__ inline float gelu_f(float x){
  float t = 0.7978845608028654f * x * (1.0f + 0.044715f*x*x);
  float e = __expf(2.0f*t);
  return x * (1.0f - __builtin_amdgcn_rcpf(e + 1.0f));
}

__device__ inline void gload_lds16(const u16* g, u16* l) {
  __builtin_amdgcn_global_load_lds(
      (__attribute__((address_space(1))) void*)(const_cast<u16*>(g)),
      (__attribute__((address_space(3))) void*)(l), 16, 0, 0);
}

// ============ Persistent streaming GEMM ============
// C[M,N] = A[M,K](bf16) * B^T-layout[N,K](bf16) + epilogue
//   EPI 0: out bf16 = acc+bias   EPI 1: out bf16 = gelu(acc+bias)   EPI 2: out f32 = acc+bias+res
// 256 blocks (1/CU, 128KB LDS), 512 threads (8 waves, 4x2 wave grid over a 128x128 tile).
// Each block owns a CONTIGUOUS col-fastest range of tiles; units = (tile, K-chunk of 128).
// 2-LDS-buffer pipeline at unit granularity:
//   vmcnt(8) -> barrier -> ds_read all frags -> lgkmcnt(0)+fence -> barrier
//   -> stage(u+2 into just-read buffer) -> 32 MFMA (+ epilogue on last chunk).
// Loads for 2 units always in flight; prologue paid ONCE per block (not per tile).
// LDS row = 128 bf16 (16 x 16B slots); swizzle phys_slot = slot ^ (row&7), applied on the
// pre-swizzled GLOBAL source (linear LDS dest, G21) and on the ds_read address.
// MFMA swapped: mfma(b, a, acc) -> C^T fragment: row = lane&15, col = (lane>>4)*4 + reg.
template<int EPI, int NC>   // NC = K/128 chunks
__global__ __launch_bounds__(512)
void gemm_stream(const u16* __restrict__ A, int lda,
                 const u16* __restrict__ Bm, int ldb, long bStride,
                 const float* __restrict__ bias,
                 const float* __restrict__ res,
                 void* __restrict__ outp, int ldo,
                 int ntM, int ntN, int nTiles,
                 int rowsValid, int batchRowStride)
{
  __shared__ alignas(16) u16 lds[2][32768];   // per buf: A = [0,16384) u16, B = [16384,32768)
  const int tid = threadIdx.x;
  const int wid = tid >> 6, lane = tid & 63;
  const int wm = wid >> 1, wn = wid & 1;      // wave grid: 4 row-groups x 2 col-groups
  const int lr = lane & 15, sl = lane >> 4;

  // balanced contiguous tile range for this block (col-fastest order => A-tile L2 reuse)
  const int nb = gridDim.x;
  const int q = nTiles / nb, rem = nTiles % nb;
  const int p = blockIdx.x;
  const int t0 = p * q + (p < rem ? p : rem);
  const int myT = q + (p < rem ? 1 : 0);
  const int U = myT * NC;

  auto stage = [&](int u, int bi) {
    const int t = t0 + u / NC, ch = u % NC;
    int rel = t; const int bz = rel / (ntM*ntN); rel -= bz*(ntM*ntN);
    const int bx = rel / ntN, by = rel - bx*ntN;
    const long rowB = (long)bz * batchRowStride + (long)bx * 128;
    const long colB = (long)by * 128;
    const u16* Bp = Bm + (long)bz * bStride;
    const int k0 = ch << 7;
#pragma unroll
    for (int i = 0; i < 4; ++i) {            // A: 32KB
      const int o16 = i*512 + tid;
      const int r = o16 >> 4, ps = o16 & 15;
      const int gc = ((ps ^ (r & 7)) << 3) + k0;
      gload_lds16(A + (rowB + r)*(long)lda + gc, &lds[bi][o16*8]);
    }
#pragma unroll
    for (int i = 0; i < 4; ++i) {            // B: 32KB
      const int o16 = i*512 + tid;
      const int r = o16 >> 4, ps = o16 & 15;
      const int gc = ((ps ^ (r & 7)) << 3) + k0;
      gload_lds16(Bp + (colB + r)*(long)ldb + gc, &lds[bi][16384 + o16*8]);
    }
  };

  f32x4 acc[2][4];
  stage(0, 0);
  stage(1, 1);

  for (int u = 0; u < U; ++u) {
    const int bi = u & 1;
    const int ch = u % NC;
    if (u == U - 1) { asm volatile("s_waitcnt vmcnt(0)" ::: "memory"); }
    else            { asm volatile("s_waitcnt vmcnt(8)" ::: "memory"); }
    __builtin_amdgcn_s_barrier();            // buf[bi] fully landed for every wave

    if (ch == 0) {
#pragma unroll
      for (int mi = 0; mi < 2; ++mi)
#pragma unroll
        for (int ni = 0; ni < 4; ++ni) acc[mi][ni] = f32x4{0.f,0.f,0.f,0.f};
    }

    // read ALL fragments of this chunk into registers
    bf16x8 fa[2][4], fb[4][4];
#pragma unroll
    for (int mi = 0; mi < 2; ++mi) {
      const int ra = wm*32 + mi*16 + lr;
#pragma unroll
      for (int ks = 0; ks < 4; ++ks) {
        const int ps = (ks*4 + sl) ^ (ra & 7);
        fa[mi][ks] = *reinterpret_cast<const bf16x8*>(&lds[bi][ra*128 + ps*8]);
      }
    }
#pragma unroll
    for (int ni = 0; ni < 4; ++ni) {
      const int rb = wn*64 + ni*16 + lr;
#pragma unroll
      for (int ks = 0; ks < 4; ++ks) {
        const int ps = (ks*4 + sl) ^ (rb & 7);
        fb[ni][ks] = *reinterpret_cast<const bf16x8*>(&lds[bi][16384 + rb*128 + ps*8]);
      }
    }
    asm volatile("s_waitcnt lgkmcnt(0)" ::: "memory");
    __builtin_amdgcn_sched_barrier(0);
    __builtin_amdgcn_s_barrier();            // all waves done reading buf[bi]

    if (u + 2 < U) stage(u + 2, bi);         // overwrite buf[bi] while we compute from regs

#pragma unroll
    for (int ks = 0; ks < 4; ++ks)
#pragma unroll
      for (int mi = 0; mi < 2; ++mi)
#pragma unroll
        for (int ni = 0; ni < 4; ++ni)       // swapped operands -> C^T fragment layout
          acc[mi][ni] = __builtin_amdgcn_mfma_f32_16x16x32_bf16(fb[ni][ks], fa[mi][ks], acc[mi][ni], 0, 0, 0);

    if (ch == NC - 1) {
      // epilogue for tile t0 + u/NC: row = lane&15, cols = (lane>>4)*4 .. +3
      const int t = t0 + u / NC;
      int rel = t; const int bz = rel / (ntM*ntN); rel -= bz*(ntM*ntN);
      const int bx = rel / ntN, by = rel - bx*ntN;
      const long rowB = (long)bz * batchRowStride + (long)bx * 128;
      const int colB = by * 128;
      const int cq = sl * 4;
#pragma unroll
      for (int mi = 0; mi < 2; ++mi) {
        const int r = wm*32 + mi*16 + lr;
        if (bx*128 + r < rowsValid) {
          const long grow = rowB + r;
#pragma unroll
          for (int ni = 0; ni < 4; ++ni) {
            const int c0 = colB + wn*64 + ni*16 + cq;
            const long oidx = grow*(long)ldo + c0;
            f32x4 v = acc[mi][ni] + *reinterpret_cast<const f32x4*>(&bias[c0]);
            if (EPI == 0) {
              uint2 pk; pk.x = cvt_pk_bf16(v[0], v[1]); pk.y = cvt_pk_bf16(v[2], v[3]);
              *reinterpret_cast<uint2*>((u16*)outp + oidx) = pk;
            } else if (EPI == 1) {
              uint2 pk; pk.x = cvt_pk_bf16(gelu_f(v[0]), gelu_f(v[1]));
              pk.y = cvt_pk_bf16(gelu_f(v[2]), gelu_f(v[3]));
              *reinterpret_cast<uint2*>((u16*)outp + oidx) = pk;
            } else {
              f32x4 rv = *reinterpret_cast<const f32x4*>((const float*)res + oidx);
              *reinterpret_cast<f32x4*>((float*)outp + oidx) = v + rv;
            }
          }
        }
      }
    }
  }
}

// ---------------- LayerNorm over C=256, one wave per token, bf16 out ----------------
__global__ __launch_bounds__(256)
void ln_kernel(const float* __restrict__ in, const float* __restrict__ g,
               const float* __restrict__ bt, u16* __restrict__ out, int M)
{
  const int wv = threadIdx.x >> 6, lane = threadIdx.x & 63;
  const int t = blockIdx.x * 4 + wv;
  if (t >= M) return;
  const float4 x = reinterpret_cast<const float4*>(in + (long)t*256)[lane];
  float s = x.x + x.y + x.z + x.w;
  float q = x.x*x.x + x.y*x.y + x.z*x.z + x.w*x.w;
#pragma unroll
  for (int o = 32; o > 0; o >>= 1) { s += __shfl_xor(s, o); q += __shfl_xor(q, o); }
  const float m  = s * (1.0f/256.0f);
  const float var = q * (1.0f/256.0f) - m*m;
  const float rs = rsqrtf(var + 1e-5f);
  const float4 gv = reinterpret_cast<const float4*>(g)[lane];
  const float4 bv = reinterpret_cast<const float4*>(bt)[lane];
  uint2 o4;
  o4.x = cvt_pk_bf16((x.x - m)*rs*gv.x + bv.x, (x.y - m)*rs*gv.y + bv.y);
  o4.y = cvt_pk_bf16((x.z - m)*rs*gv.z + bv.z, (x.w - m)*rs*gv.w + bv.w);
  *reinterpret_cast<uint2*>(out + (long)t*256 + lane*4) = o4;
}

// -------- fused per-head LN(k), LN(v) + kv[b,h] += k^T v / N (atomic f32) --------
__global__ __launch_bounds__(256)
void kv_kernel(const u16* __restrict__ QKV,
               const float* __restrict__ kg, const float* __restrict__ kb,
               const float* __restrict__ vg, const float* __restrict__ vb,
               float* __restrict__ kvout)
{
  const int bh = blockIdx.x, b = bh >> 3, h = bh & 7;
  const int tid = threadIdx.x;
  __shared__ u16 kls[256][32];
  __shared__ u16 vls[256][32];
  __shared__ float sg[4][32];
  if (tid < 32) {
    sg[0][tid] = kg[h*32 + tid];
    sg[1][tid] = kb[h*32 + tid];
    sg[2][tid] = vg[h*32 + tid];
    sg[3][tid] = vb[h*32 + tid];
  }
  const int d = tid >> 3, e0 = (tid & 7) * 4;
  float a0=0, a1=0, a2=0, a3=0;

  for (int sub = 0; sub < 2; ++sub) {
    const int r = blockIdx.y * 512 + sub * 256 + tid;
    __syncthreads();
    if (r < NTOK) {
      const u16* rowp = QKV + (long)(b*NTOK + r)*768;
#pragma unroll
      for (int kv2 = 0; kv2 < 2; ++kv2) {
        const u16* p = rowp + (kv2 ? 512 : 256) + h*32;
        float xv[32]; float s = 0.f;
#pragma unroll
        for (int q4 = 0; q4 < 4; ++q4) {
          u16x8 u = *reinterpret_cast<const u16x8*>(p + q4*8);
#pragma unroll
          for (int j = 0; j < 8; ++j) { float f = bf2f(u[j]); xv[q4*8+j] = f; s += f; }
        }
        const float m = s * (1.0f/32.0f);
        float vv = 0.f;
#pragma unroll
        for (int j = 0; j < 32; ++j) { float d2 = xv[j]-m; vv += d2*d2; }
        const float rs = rsqrtf(vv*(1.0f/32.0f) + 1e-5f);
        const float* gg = sg[kv2 ? 2 : 0];
        const float* bb = sg[kv2 ? 3 : 1];
        u16 (*dst)[32] = kv2 ? vls : kls;
#pragma unroll
        for (int j = 0; j < 32; ++j) dst[tid][j] = f2bf((xv[j]-m)*rs*gg[j] + bb[j]);
      }
    } else {
#pragma unroll
      for (int j = 0; j < 32; ++j) { kls[tid][j] = 0; vls[tid][j] = 0; }
    }
    __syncthreads();
#pragma unroll 4
    for (int rr = 0; rr < 256; ++rr) {
      const float kd = bf2f(kls[rr][d]);
      u16x4 v4 = *reinterpret_cast<const u16x4*>(&vls[rr][e0]);
      a0 += kd * bf2f(v4[0]); a1 += kd * bf2f(v4[1]);
      a2 += kd * bf2f(v4[2]); a3 += kd * bf2f(v4[3]);
    }
  }
  const float sc = 1.0f / (float)NTOK;
  float* o = kvout + (long)bh*1024 + d*32 + e0;
  atomicAdd(o+0, a0*sc); atomicAdd(o+1, a1*sc);
  atomicAdd(o+2, a2*sc); atomicAdd(o+3, a3*sc);
}

// -------- Wo_eff_t[b][c][r=h*32+d] = sum_e kv[b,h,d,e] * Wo[h*32+e][c] (bf16, B^T layout) -----
__global__ __launch_bounds__(256)
void woeff_kernel(const float* __restrict__ kv, const float* __restrict__ Wo,
                  u16* __restrict__ Woet)
{
  const int b = blockIdx.x >> 8, c = blockIdx.x & 255;
  const int rtid = threadIdx.x;
  const int h = rtid >> 5, dd = rtid & 31;
  const float* kvp = kv + ((long)(b*8 + h)*32 + dd)*32;
  float s = 0.f;
#pragma unroll 8
  for (int e = 0; e < 32; ++e) s += kvp[e] * Wo[(h*32 + e)*256 + c];
  Woet[(long)(b*256 + c)*256 + rtid] = f2bf(s);
}

// ---------------- prep kernels ----------------
__global__ void zero_f32(float* p, int n) {
  int i = blockIdx.x*blockDim.x + threadIdx.x; if (i < n) p[i] = 0.f;
}
__global__ void concat_bias(const float* bq, const float* bk, const float* bv, float* o) {
  int i = threadIdx.x;
  o[i] = (i < 256) ? bq[i] : ((i < 512) ? bk[i-256] : bv[i-512]);
}
__global__ __launch_bounds__(256)
void transpose_cvt(const float* __restrict__ src, u16* __restrict__ dst, int R, int C) {
  __shared__ float t[32][33];
  const int tc = blockIdx.x * 32, tr = blockIdx.y * 32;
  const int lx = threadIdx.x & 31, ly = threadIdx.x >> 5;
#pragma unroll
  for (int i = 0; i < 32; i += 8)
    t[ly + i][lx] = src[(long)(tr + ly + i)*C + tc + lx];
  __syncthreads();
#pragma unroll
  for (int i = 0; i < 32; i += 8)
    dst[(long)(tc + ly + i)*R + tr + lx] = f2bf(t[lx][ly + i]);
}

// ---------------- launch ----------------
extern "C" void kernel_launch(void* const* d_in, const int* in_sizes, int n_in,
                              void* d_out, int out_size, void* d_ws, size_t ws_size,
                              hipStream_t stream)
{
  const float* fx    = (const float*)d_in[0];
  const float* ln1_g = (const float*)d_in[1];
  const float* ln1_b = (const float*)d_in[2];
  const float* Wq = (const float*)d_in[3];
  const float* bq = (const float*)d_in[4];
  const float* Wk = (const float*)d_in[5];
  const float* bk = (const float*)d_in[6];
  const float* Wv = (const float*)d_in[7];
  const float* bv = (const float*)d_in[8];
  const float* Wo = (const float*)d_in[9];
  const float* bo = (const float*)d_in[10];
  const float* kg  = (const float*)d_in[11];
  const float* kbb = (const float*)d_in[12];
  const float* vg  = (const float*)d_in[13];
  const float* vbb = (const float*)d_in[14];
  const float* ln2_g = (const float*)d_in[15];
  const float* ln2_b = (const float*)d_in[16];
  const float* W1 = (const float*)d_in[17];
  const float* b1 = (const float*)d_in[18];
  const float* W2 = (const float*)d_in[19];
  const float* b2 = (const float*)d_in[20];
  float* outF = (float*)d_out;

  char* ws = (char*)d_ws;
  size_t off = 0;
  auto alloc = [&](size_t bytes) { char* p = ws + off; off += (bytes + 255) & ~(size_t)255; return p; };
  u16* bufX   = (u16*)alloc((size_t)MROWS*256*2);
  u16* bufQKV = (u16*)alloc((size_t)MROWS*768*2);
  u16* bufH   = (u16*)alloc((size_t)MROWS*1024*2);
  u16* Wqkv_t = (u16*)alloc(768*256*2);
  u16* W1_t   = (u16*)alloc(1024*256*2);
  u16* W2_t   = (u16*)alloc(256*1024*2);
  u16* Woe_t  = (u16*)alloc((size_t)8*256*256*2);
  float* kvb  = (float*)alloc((size_t)64*1024*4);
  float* bqkv = (float*)alloc(768*4);
  (void)ws_size; (void)out_size; (void)n_in; (void)in_sizes;

  // prep
  zero_f32<<<256, 256, 0, stream>>>(kvb, 65536);
  concat_bias<<<1, 768, 0, stream>>>(bq, bk, bv, bqkv);
  transpose_cvt<<<dim3(8,8),  256, 0, stream>>>(Wq, Wqkv_t,          256, 256);
  transpose_cvt<<<dim3(8,8),  256, 0, stream>>>(Wk, Wqkv_t + 65536,  256, 256);
  transpose_cvt<<<dim3(8,8),  256, 0, stream>>>(Wv, Wqkv_t + 131072, 256, 256);
  transpose_cvt<<<dim3(32,8), 256, 0, stream>>>(W1, W1_t, 256, 1024);
  transpose_cvt<<<dim3(8,32), 256, 0, stream>>>(W2, W2_t, 1024, 256);

  // x = LN1(fx)
  ln_kernel<<<MTOT/4, 256, 0, stream>>>(fx, ln1_g, ln1_b, bufX, MTOT);

  // QKV = x @ [Wq|Wk|Wv] + bias : M=57800(452 tiles), N=768(6), K=256(NC=2)
  gemm_stream<0,2><<<256, 512, 0, stream>>>(
      bufX, 256, Wqkv_t, 256, 0, bqkv, nullptr, bufQKV, 768,
      452, 6, 452*6, MTOT, 0);

  // kv[b,h] = LN(k)^T LN(v) / N
  kv_kernel<<<dim3(64, 15), 256, 0, stream>>>(bufQKV, kg, kbb, vg, vbb, kvb);

  // Wo_eff per batch
  woeff_kernel<<<2048, 256, 0, stream>>>(kvb, Wo, Woe_t);

  // d_out = fx + q @ Wo_eff[b] + bo : batched, M=7225(57)/batch, N=256(2), K=256(NC=2)
  gemm_stream<2,2><<<256, 512, 0, stream>>>(
      bufQKV, 768, Woe_t, 256, 65536, bo, fx, outF, 256,
      57, 2, 8*57*2, NTOK, NTOK);

  // x2 = LN2(d_out)
  ln_kernel<<<MTOT/4, 256, 0, stream>>>(outF, ln2_g, ln2_b, bufX, MTOT);

  // H = gelu(x2 @ W1 + b1) : N=1024(8), K=256(NC=2)
  gemm_stream<1,2><<<256, 512, 0, stream>>>(
      bufX, 256, W1_t, 256, 0, b1, nullptr, bufH, 1024,
      452, 8, 452*8, MTOT, 0);

  // d_out = d_out + H @ W2 + b2 : N=256(2), K=1024(NC=8)
  gemm_stream<2,8><<<256, 512, 0, stream>>>(
      bufH, 1024, W2_t, 1024, 0, b2, outF, outF, 256,
      452, 2, 452*2, MTOT, 0);
}

// Round 6
// 374.733 us; speedup vs baseline: 1.0436x; 1.0436x over previous
//
#include <hip/hip_runtime.h>
#include <hip/hip_bf16.h>
#include <stdint.h>

#define B_ 8
#define NTOK 7225
#define MTOT (B_*NTOK)      // 57800
#define MROWS 58368         // padded rows for all M-row buffers (228*256)
#define MT_FULL 226         // ceil(57800/256)
#define MT_BATCH 29         // ceil(7225/256)

typedef unsigned short u16;
typedef u16 u16x8 __attribute__((ext_vector_type(8)));
typedef u16 u16x4 __attribute__((ext_vector_type(4)));
typedef __bf16 bf16x8 __attribute__((ext_vector_type(8)));
typedef float f32x4 __attribute__((ext_vector_type(4)));

__device__ inline float bf2f(u16 u){ union{float f;uint32_t i;}c; c.i=((uint32_t)u)<<16; return c.f; }
__device__ inline u16 f2bf(float f){ union{float f;uint32_t i;}c; c.f=f; uint32_t x=c.i;
                                     return (u16)((x + 0x7fffu + ((x>>16)&1u))>>16); }
__device__ inline uint32_t cvt_pk_bf16(float a, float b){
  uint32_t r; asm("v_cvt_pk_bf16_f32 %0, %1, %2" : "=v"(r) : "v"(a), "v"(b)); return r;
}
// fast tanh-gelu: 0.5x(1+tanh t) == x * (1 - 1/(exp(2t)+1))
__device__ inline float gelu_f(float x){
  float t = 0.7978845608028654f * x * (1.0f + 0.044715f*x*x);
  float e = __expf(2.0f*t);
  return x * (1.0f - __builtin_amdgcn_rcpf(e + 1.0f));
}

__device__ inline void gload_lds16(const u16* g, u16* l) {
  __builtin_amdgcn_global_load_lds(
      (__attribute__((address_space(1))) void*)(const_cast<u16*>(g)),
      (__attribute__((address_space(3))) void*)(l), 16, 0, 0);
}

// ============ 256x256-tile GEMM (R3-proven LDS geometry, 8 waves) ============
// C[M,N] = A[M,K](bf16) * B^T-layout[N,K](bf16) + epilogue
//   EPI 0: bf16 = acc+bias   EPI 1: bf16 = gelu(acc+bias)   EPI 2: f32 = acc+bias+res
// 512 threads = 8 waves in 2Mx4N grid; wave tile 128x64 (8x4 fragments).
// BK=64 staged as two [256][32]-u16 sub-chunks (64B rows -> measured-zero-conflict
// swizzle: phys_slot = logical_slot ^ ((row>>1)&3), pre-applied on GLOBAL col, LDS linear).
// 2-buffer loop: sync; stage(next); compute(cur).  LDS = 2*2*16KB*2 = 128KB, 1 block/CU.
// MFMA swapped: mfma(b, a, acc) -> C^T fragment: row = lane&15, col = (lane>>4)*4 + reg.
template<int EPI>
__global__ __launch_bounds__(512, 2)
void gemm256(const u16* __restrict__ A, int lda,
             const u16* __restrict__ Bm, int ldb, long bStride,
             const float* __restrict__ bias, int biasStride,
             const float* __restrict__ res,
             void* __restrict__ outp, int ldo,
             int K, int rowsValid, int batchRowStride)
{
  __shared__ alignas(16) u16 As[2][2][256][32];
  __shared__ alignas(16) u16 Bs[2][2][256][32];
  const int tid = threadIdx.x;
  const int wid = tid >> 6, lane = tid & 63;
  const int wm = wid >> 2, wn = wid & 3;

  // bijective XCD swizzle (m204) over x,y
  const int gx = gridDim.x, gy = gridDim.y;
  const int n = gx * gy;
  const int flat = blockIdx.y * gx + blockIdx.x;
  const int qq = n >> 3, rr = n & 7;
  const int xcd = flat & 7, pos = flat >> 3;
  const int swz = (xcd < rr ? xcd*(qq+1) : rr*(qq+1) + (xcd-rr)*qq) + pos;
  const int bx = swz / gy, by = swz % gy;
  const int bz = blockIdx.z;

  const long rowBase = (long)bz * batchRowStride + (long)bx * 256;
  const int colBase = by * 256;
  const u16* Bp = Bm + (long)bz * bStride;
  const float* biasP = bias + bz * biasStride;

  const int srow = lane >> 2;                              // 0..15
  const int scol = ((lane & 3) ^ ((lane >> 3) & 3)) * 8;   // pre-swizzled global slot
  const int NT = K >> 6;

  auto stage = [&](int bf, int kt) {
    const int k0 = kt << 6;
#pragma unroll
    for (int i = 0; i < 4; ++i) {
      const int u = wid*4 + i;                 // 0..31, wave-uniform
      const int sub = u >> 4, r0 = (u & 15) * 16;
      const int r = r0 + srow;
      gload_lds16(A + (rowBase + r)*(long)lda + k0 + sub*32 + scol, &As[bf][sub][r0][0]);
    }
#pragma unroll
    for (int i = 0; i < 4; ++i) {
      const int u = wid*4 + i;
      const int sub = u >> 4, r0 = (u & 15) * 16;
      const int r = r0 + srow;
      gload_lds16(Bp + (long)(colBase + r)*ldb + k0 + sub*32 + scol, &Bs[bf][sub][r0][0]);
    }
  };

  f32x4 acc[8][4] = {};
  const int lr = lane & 15;
  const int sl = lane >> 4;
  const int sp = (sl ^ ((lr >> 1) & 3)) * 8;   // phys slot*8 for all fragment reads

  auto compute = [&](int bf) {
#pragma unroll
    for (int sub = 0; sub < 2; ++sub) {
      bf16x8 a[8], b[4];
#pragma unroll
      for (int mi = 0; mi < 8; ++mi)
        a[mi] = *reinterpret_cast<const bf16x8*>(&As[bf][sub][wm*128 + mi*16 + lr][sp]);
#pragma unroll
      for (int ni = 0; ni < 4; ++ni)
        b[ni] = *reinterpret_cast<const bf16x8*>(&Bs[bf][sub][wn*64 + ni*16 + lr][sp]);
#pragma unroll
      for (int mi = 0; mi < 8; ++mi)
#pragma unroll
        for (int ni = 0; ni < 4; ++ni)   // swapped -> C^T fragment layout
          acc[mi][ni] = __builtin_amdgcn_mfma_f32_16x16x32_bf16(b[ni], a[mi], acc[mi][ni], 0, 0, 0);
    }
  };

  stage(0, 0);
  for (int kt = 0; kt < NT; ++kt) {
    __syncthreads();                         // stage(kt) landed; buf (kt+1)&1 free to overwrite
    if (kt + 1 < NT) stage((kt + 1) & 1, kt + 1);
    compute(kt & 1);
  }

  // epilogue: row = lane&15, cols = (lane>>4)*4 .. +3
  const int cq = sl * 4;
#pragma unroll
  for (int mi = 0; mi < 8; ++mi) {
    const int r = wm*128 + mi*16 + lr;
    if (bx*256 + r < rowsValid) {
      const long grow = rowBase + r;
#pragma unroll
      for (int ni = 0; ni < 4; ++ni) {
        const int c0 = colBase + wn*64 + ni*16 + cq;
        const long oidx = grow*(long)ldo + c0;
        f32x4 v = acc[mi][ni] + *reinterpret_cast<const f32x4*>(&biasP[c0]);
        if (EPI == 0) {
          uint2 pk; pk.x = cvt_pk_bf16(v[0], v[1]); pk.y = cvt_pk_bf16(v[2], v[3]);
          *reinterpret_cast<uint2*>((u16*)outp + oidx) = pk;
        } else if (EPI == 1) {
          uint2 pk; pk.x = cvt_pk_bf16(gelu_f(v[0]), gelu_f(v[1]));
          pk.y = cvt_pk_bf16(gelu_f(v[2]), gelu_f(v[3]));
          *reinterpret_cast<uint2*>((u16*)outp + oidx) = pk;
        } else {
          f32x4 rv = *reinterpret_cast<const f32x4*>((const float*)res + oidx);
          *reinterpret_cast<f32x4*>((float*)outp + oidx) = v + rv;
        }
      }
    }
  }
}

// ---------------- LayerNorm over C=256, one wave per token, bf16 out ----------------
__global__ __launch_bounds__(256)
void ln_kernel(const float* __restrict__ in, const float* __restrict__ g,
               const float* __restrict__ bt, u16* __restrict__ out, int M)
{
  const int wv = threadIdx.x >> 6, lane = threadIdx.x & 63;
  const int t = blockIdx.x * 4 + wv;
  if (t >= M) return;
  const float4 x = reinterpret_cast<const float4*>(in + (long)t*256)[lane];
  float s = x.x + x.y + x.z + x.w;
  float q = x.x*x.x + x.y*x.y + x.z*x.z + x.w*x.w;
#pragma unroll
  for (int o = 32; o > 0; o >>= 1) { s += __shfl_xor(s, o); q += __shfl_xor(q, o); }
  const float m  = s * (1.0f/256.0f);
  const float var = q * (1.0f/256.0f) - m*m;
  const float rs = rsqrtf(var + 1e-5f);
  const float4 gv = reinterpret_cast<const float4*>(g)[lane];
  const float4 bv = reinterpret_cast<const float4*>(bt)[lane];
  uint2 o4;
  o4.x = cvt_pk_bf16((x.x - m)*rs*gv.x + bv.x, (x.y - m)*rs*gv.y + bv.y);
  o4.y = cvt_pk_bf16((x.z - m)*rs*gv.z + bv.z, (x.w - m)*rs*gv.w + bv.w);
  *reinterpret_cast<uint2*>(out + (long)t*256 + lane*4) = o4;
}

// -------- fused per-head LN(k), LN(v) + kv[b,h] += k^T v / N (atomic f32) --------
// KV buffer layout: [M][512] = [k(256) | v(256)]
__global__ __launch_bounds__(256)
void kv_kernel(const u16* __restrict__ KV,
               const float* __restrict__ kg, const float* __restrict__ kb,
               const float* __restrict__ vg, const float* __restrict__ vb,
               float* __restrict__ kvout)
{
  const int bh = blockIdx.x, b = bh >> 3, h = bh & 7;
  const int tid = threadIdx.x;
  __shared__ u16 kls[256][32];
  __shared__ u16 vls[256][32];
  __shared__ float sg[4][32];
  if (tid < 32) {
    sg[0][tid] = kg[h*32 + tid];
    sg[1][tid] = kb[h*32 + tid];
    sg[2][tid] = vg[h*32 + tid];
    sg[3][tid] = vb[h*32 + tid];
  }
  const int d = tid >> 3, e0 = (tid & 7) * 4;
  float a0=0, a1=0, a2=0, a3=0;

  for (int sub = 0; sub < 2; ++sub) {
    const int r = blockIdx.y * 512 + sub * 256 + tid;
    __syncthreads();
    if (r < NTOK) {
      const u16* rowp = KV + (long)(b*NTOK + r)*512;
#pragma unroll
      for (int kv2 = 0; kv2 < 2; ++kv2) {
        const u16* p = rowp + (kv2 ? 256 : 0) + h*32;
        float xv[32]; float s = 0.f;
#pragma unroll
        for (int q4 = 0; q4 < 4; ++q4) {
          u16x8 u = *reinterpret_cast<const u16x8*>(p + q4*8);
#pragma unroll
          for (int j = 0; j < 8; ++j) { float f = bf2f(u[j]); xv[q4*8+j] = f; s += f; }
        }
        const float m = s * (1.0f/32.0f);
        float vv = 0.f;
#pragma unroll
        for (int j = 0; j < 32; ++j) { float d2 = xv[j]-m; vv += d2*d2; }
        const float rs = rsqrtf(vv*(1.0f/32.0f) + 1e-5f);
        const float* gg = sg[kv2 ? 2 : 0];
        const float* bb = sg[kv2 ? 3 : 1];
        u16 (*dst)[32] = kv2 ? vls : kls;
#pragma unroll
        for (int j = 0; j < 32; ++j) dst[tid][j] = f2bf((xv[j]-m)*rs*gg[j] + bb[j]);
      }
    } else {
#pragma unroll
      for (int j = 0; j < 32; ++j) { kls[tid][j] = 0; vls[tid][j] = 0; }
    }
    __syncthreads();
#pragma unroll 4
    for (int rr = 0; rr < 256; ++rr) {
      const float kd = bf2f(kls[rr][d]);
      u16x4 v4 = *reinterpret_cast<const u16x4*>(&vls[rr][e0]);
      a0 += kd * bf2f(v4[0]); a1 += kd * bf2f(v4[1]);
      a2 += kd * bf2f(v4[2]); a3 += kd * bf2f(v4[3]);
    }
  }
  const float sc = 1.0f / (float)NTOK;
  float* o = kvout + (long)bh*1024 + d*32 + e0;
  atomicAdd(o+0, a0*sc); atomicAdd(o+1, a1*sc);
  atomicAdd(o+2, a2*sc); atomicAdd(o+3, a3*sc);
}

// -------- Woe_t[b][c][j=h*32+d] = sum_e kv[b,h,d,e] * Wo[h*32+e][c]  (= kvWo[j][c], bf16) ----
__global__ __launch_bounds__(256)
void woeff_kernel(const float* __restrict__ kv, const float* __restrict__ Wo,
                  u16* __restrict__ Woet)
{
  const int b = blockIdx.x >> 8, c = blockIdx.x & 255;
  const int rtid = threadIdx.x;
  const int h = rtid >> 5, dd = rtid & 31;
  const float* kvp = kv + ((long)(b*8 + h)*32 + dd)*32;
  float s = 0.f;
#pragma unroll 8
  for (int e = 0; e < 32; ++e) s += kvp[e] * Wo[(h*32 + e)*256 + c];
  Woet[(long)(b*256 + c)*256 + rtid] = f2bf(s);
}

// -------- Watt[b][c][k] = sum_j Wq[k,j] * kvWo[b][j,c]  (B^T layout for att GEMM) --------
__global__ __launch_bounds__(256)
void watt_kernel(const u16* __restrict__ wq_bf, const u16* __restrict__ Woet,
                 u16* __restrict__ Watt)
{
  const int b = blockIdx.x >> 8, c = blockIdx.x & 255;
  const int k = threadIdx.x;
  const u16* wr = wq_bf + (long)k*256;
  const u16* er = Woet + ((long)(b*256 + c))*256;
  float s = 0.f;
#pragma unroll 4
  for (int j0 = 0; j0 < 256; j0 += 8) {
    u16x8 wv = *reinterpret_cast<const u16x8*>(wr + j0);
    u16x8 ev = *reinterpret_cast<const u16x8*>(er + j0);
#pragma unroll
    for (int j = 0; j < 8; ++j) s += bf2f(wv[j]) * bf2f(ev[j]);
  }
  Watt[((long)(b*256 + c))*256 + k] = f2bf(s);
}

// -------- be[b][c] = sum_j bq[j] * kvWo[b][j,c] + bo[c] --------
__global__ __launch_bounds__(256)
void be_kernel(const float* __restrict__ bq, const float* __restrict__ bo,
               const u16* __restrict__ Woet, float* __restrict__ be)
{
  const int b = blockIdx.x, c = threadIdx.x;
  const u16* er = Woet + ((long)(b*256 + c))*256;
  float s = bo[c];
#pragma unroll 4
  for (int j0 = 0; j0 < 256; j0 += 8) {
    u16x8 ev = *reinterpret_cast<const u16x8*>(er + j0);
#pragma unroll
    for (int j = 0; j < 8; ++j) s += bq[j0+j] * bf2f(ev[j]);
  }
  be[b*256 + c] = s;
}

// ---------------- prep kernels ----------------
__global__ void zero_f32(float* p, int n) {
  int i = blockIdx.x*blockDim.x + threadIdx.x; if (i < n) p[i] = 0.f;
}
__global__ void concat_bias2(const float* bk, const float* bv, float* o) {
  int i = threadIdx.x;
  o[i] = (i < 256) ? bk[i] : bv[i-256];
}
__global__ void cvt_bf(const float* __restrict__ src, u16* __restrict__ dst, int n) {
  int i = blockIdx.x*blockDim.x + threadIdx.x; if (i < n) dst[i] = f2bf(src[i]);
}
__global__ __launch_bounds__(256)
void transpose_cvt(const float* __restrict__ src, u16* __restrict__ dst, int R, int C) {
  __shared__ float t[32][33];
  const int tc = blockIdx.x * 32, tr = blockIdx.y * 32;
  const int lx = threadIdx.x & 31, ly = threadIdx.x >> 5;
#pragma unroll
  for (int i = 0; i < 32; i += 8)
    t[ly + i][lx] = src[(long)(tr + ly + i)*C + tc + lx];
  __syncthreads();
#pragma unroll
  for (int i = 0; i < 32; i += 8)
    dst[(long)(tc + ly + i)*R + tr + lx] = f2bf(t[lx][ly + i]);
}

// ---------------- launch ----------------
extern "C" void kernel_launch(void* const* d_in, const int* in_sizes, int n_in,
                              void* d_out, int out_size, void* d_ws, size_t ws_size,
                              hipStream_t stream)
{
  const float* fx    = (const float*)d_in[0];
  const float* ln1_g = (const float*)d_in[1];
  const float* ln1_b = (const float*)d_in[2];
  const float* Wq = (const float*)d_in[3];
  const float* bq = (const float*)d_in[4];
  const float* Wk = (const float*)d_in[5];
  const float* bk = (const float*)d_in[6];
  const float* Wv = (const float*)d_in[7];
  const float* bv = (const float*)d_in[8];
  const float* Wo = (const float*)d_in[9];
  const float* bo = (const float*)d_in[10];
  const float* kg  = (const float*)d_in[11];
  const float* kbb = (const float*)d_in[12];
  const float* vg  = (const float*)d_in[13];
  const float* vbb = (const float*)d_in[14];
  const float* ln2_g = (const float*)d_in[15];
  const float* ln2_b = (const float*)d_in[16];
  const float* W1 = (const float*)d_in[17];
  const float* b1 = (const float*)d_in[18];
  const float* W2 = (const float*)d_in[19];
  const float* b2 = (const float*)d_in[20];
  float* outF = (float*)d_out;

  char* ws = (char*)d_ws;
  size_t off = 0;
  auto alloc = [&](size_t bytes) { char* p = ws + off; off += (bytes + 255) & ~(size_t)255; return p; };
  u16* bufX   = (u16*)alloc((size_t)MROWS*256*2);   // LN1 out, later LN2 out
  u16* bufKV  = (u16*)alloc((size_t)MROWS*512*2);
  u16* bufH   = (u16*)alloc((size_t)MROWS*1024*2);
  u16* Wkv_t  = (u16*)alloc(512*256*2);
  u16* W1_t   = (u16*)alloc(1024*256*2);
  u16* W2_t   = (u16*)alloc(256*1024*2);
  u16* Woe_t  = (u16*)alloc((size_t)8*256*256*2);
  u16* Watt   = (u16*)alloc((size_t)8*256*256*2);
  u16* wq_bf  = (u16*)alloc(256*256*2);
  float* kvb  = (float*)alloc((size_t)64*1024*4);
  float* bkv  = (float*)alloc(512*4);
  float* be   = (float*)alloc(8*256*4);
  (void)ws_size; (void)out_size; (void)n_in; (void)in_sizes;

  // prep
  zero_f32<<<256, 256, 0, stream>>>(kvb, 65536);
  concat_bias2<<<1, 512, 0, stream>>>(bk, bv, bkv);
  cvt_bf<<<256, 256, 0, stream>>>(Wq, wq_bf, 65536);
  transpose_cvt<<<dim3(8,8),  256, 0, stream>>>(Wk, Wkv_t,         256, 256);
  transpose_cvt<<<dim3(8,8),  256, 0, stream>>>(Wv, Wkv_t + 65536, 256, 256);
  transpose_cvt<<<dim3(32,8), 256, 0, stream>>>(W1, W1_t, 256, 1024);
  transpose_cvt<<<dim3(8,32), 256, 0, stream>>>(W2, W2_t, 1024, 256);

  // x = LN1(fx)
  ln_kernel<<<MTOT/4, 256, 0, stream>>>(fx, ln1_g, ln1_b, bufX, MTOT);

  // KV = x @ [Wk|Wv] + [bk|bv] : M-tiles 226, N-tiles 2, K=256
  gemm256<0><<<dim3(MT_FULL, 2, 1), 512, 0, stream>>>(
      bufX, 256, Wkv_t, 256, 0, bkv, 0, nullptr, bufKV, 512, 256, MTOT, 0);

  // kv[b,h] = LN(k)^T LN(v) / N
  kv_kernel<<<dim3(64, 15), 256, 0, stream>>>(bufKV, kg, kbb, vg, vbb, kvb);

  // kvWo, W_att, be
  woeff_kernel<<<2048, 256, 0, stream>>>(kvb, Wo, Woe_t);
  watt_kernel<<<2048, 256, 0, stream>>>(wq_bf, Woe_t, Watt);
  be_kernel<<<8, 256, 0, stream>>>(bq, bo, Woe_t, be);

  // out = fx + x @ W_att[b] + be[b] : per-batch M-tiles 29, N-tiles 1, K=256
  gemm256<2><<<dim3(MT_BATCH, 1, 8), 512, 0, stream>>>(
      bufX, 256, Watt, 256, 65536, be, 256, fx, outF, 256, 256, NTOK, NTOK);

  // x2 = LN2(out)
  ln_kernel<<<MTOT/4, 256, 0, stream>>>(outF, ln2_g, ln2_b, bufX, MTOT);

  // H = gelu(x2 @ W1 + b1) : N-tiles 4, K=256
  gemm256<1><<<dim3(MT_FULL, 4, 1), 512, 0, stream>>>(
      bufX, 256, W1_t, 256, 0, b1, 0, nullptr, bufH, 1024, 256, MTOT, 0);

  // out = out + H @ W2 + b2 : N-tiles 1, K=1024
  gemm256<2><<<dim3(MT_FULL, 1, 1), 512, 0, stream>>>(
      bufH, 1024, W2_t, 1024, 0, b2, 0, outF, outF, 256, 1024, MTOT, 0);
}

// Round 7
// 356.324 us; speedup vs baseline: 1.0975x; 1.0517x over previous
//
#include <hip/hip_runtime.h>
#include <hip/hip_bf16.h>
#include <stdint.h>

#define B_ 8
#define NTOK 7225
#define MTOT (B_*NTOK)      // 57800
#define MROWS 58368         // padded rows for all M-row buffers (228*256)
#define MT_FULL 226         // ceil(57800/256)
#define MT_BATCH 29         // ceil(7225/256)

typedef unsigned short u16;
typedef u16 u16x8 __attribute__((ext_vector_type(8)));
typedef u16 u16x4 __attribute__((ext_vector_type(4)));
typedef __bf16 bf16x8 __attribute__((ext_vector_type(8)));
typedef float f32x4 __attribute__((ext_vector_type(4)));

__device__ inline float bf2f(u16 u){ union{float f;uint32_t i;}c; c.i=((uint32_t)u)<<16; return c.f; }
__device__ inline u16 f2bf(float f){ union{float f;uint32_t i;}c; c.f=f; uint32_t x=c.i;
                                     return (u16)((x + 0x7fffu + ((x>>16)&1u))>>16); }
__device__ inline uint32_t cvt_pk_bf16(float a, float b){
  uint32_t r; asm("v_cvt_pk_bf16_f32 %0, %1, %2" : "=v"(r) : "v"(a), "v"(b)); return r;
}
// fast tanh-gelu: 0.5x(1+tanh t) == x * (1 - 1/(exp(2t)+1))
__device__ inline float gelu_f(float x){
  float t = 0.7978845608028654f * x * (1.0f + 0.044715f*x*x);
  float e = __expf(2.0f*t);
  return x * (1.0f - __builtin_amdgcn_rcpf(e + 1.0f));
}

__device__ inline void gload_lds16(const u16* g, u16* l) {
  __builtin_amdgcn_global_load_lds(
      (__attribute__((address_space(1))) void*)(const_cast<u16*>(g)),
      (__attribute__((address_space(3))) void*)(l), 16, 0, 0);
}

// ============ 256x256-tile GEMM, phase-split counted-vmcnt schedule (T3+T4+T5) ============
// C[M,N] = A[M,K](bf16) * B^T-layout[N,K](bf16) + epilogue
//   EPI 0: bf16 = acc+bias   EPI 1: bf16 = gelu(acc+bias)   EPI 2: f32 = acc+bias+res
// 512 threads = 8 waves (2M x 4N), wave tile 128x64. K-tile BK=64 split in 2 sub-chunks
// ([256][32] u16, 64B rows, measured-zero-conflict swizzle phys_slot = slot ^ ((row>>1)&3),
// pre-applied on the GLOBAL col; LDS dest linear per G21). 4 half-tiles per K-tile:
// sel 0..3 = {A-sub0, B-sub0, A-sub1, B-sub1}, 16KB each, 2 gload_lds/thread.
//
// 4 phases per K-tile; phase body:
//   vmcnt(N) -> s_barrier -> ds_read frags (4 or 8 b128) -> stage half sel=ph of K-tile kt+1
//   -> lgkmcnt(0)+sched_barrier -> setprio(1) 16 MFMA setprio(0)
// Counted waits (never 0 in steady state): p0:4  p1:6  p2:4 (last tile: 0)  p3:6.
// Stage stream is 4 halves ahead; per-phase barrier bounds wave skew so a staged half is
// never written while any wave still reads its previous contents (disjoint-halves at the
// K-tile boundary; A1 overwrite is 3 barriers after its last read).
// MFMA swapped: mfma(b, a, acc) -> C^T fragment: row = lane&15, col = (lane>>4)*4 + reg.
template<int EPI>
__global__ __launch_bounds__(512, 2)
void gemm256(const u16* __restrict__ A, int lda,
             const u16* __restrict__ Bm, int ldb, long bStride,
             const float* __restrict__ bias, int biasStride,
             const float* __restrict__ res,
             void* __restrict__ outp, int ldo,
             int K, int rowsValid, int batchRowStride)
{
  __shared__ alignas(16) u16 As[2][2][256][32];
  __shared__ alignas(16) u16 Bs[2][2][256][32];
  const int tid = threadIdx.x;
  const int wid = tid >> 6, lane = tid & 63;
  const int wm = wid >> 2, wn = wid & 3;

  // bijective XCD swizzle (m204) over x,y
  const int gx = gridDim.x, gy = gridDim.y;
  const int n = gx * gy;
  const int flat = blockIdx.y * gx + blockIdx.x;
  const int qq = n >> 3, rr = n & 7;
  const int xcd = flat & 7, pos = flat >> 3;
  const int swz = (xcd < rr ? xcd*(qq+1) : rr*(qq+1) + (xcd-rr)*qq) + pos;
  const int bx = swz / gy, by = swz % gy;
  const int bz = blockIdx.z;

  const long rowBase = (long)bz * batchRowStride + (long)bx * 256;
  const int colBase = by * 256;
  const u16* Bp = Bm + (long)bz * bStride;
  const float* biasP = bias + bz * biasStride;

  const int srow = lane >> 2;                              // 0..15
  const int scol = ((lane & 3) ^ ((lane >> 3) & 3)) * 8;   // pre-swizzled global slot
  const int NT = K >> 6;

  // stage one 16KB half-tile: sel 0=A-sub0 1=B-sub0 2=A-sub1 3=B-sub1
  auto stageHalf = [&](int bf, int kt, int sel) {
    const int sub = sel >> 1;
    const int k0 = (kt << 6) + sub*32 + scol;
#pragma unroll
    for (int i = 0; i < 2; ++i) {
      const int r0 = (wid*2 + i)*16;
      if ((sel & 1) == 0)
        gload_lds16(A + (rowBase + r0 + srow)*(long)lda + k0, &As[bf][sub][r0][0]);
      else
        gload_lds16(Bp + (long)(colBase + r0 + srow)*ldb + k0, &Bs[bf][sub][r0][0]);
    }
  };

  f32x4 acc[8][4] = {};
  bf16x8 afr[4], bfr[4];
  const int lr = lane & 15;
  const int sl = lane >> 4;
  const int sp = (sl ^ ((lr >> 1) & 3)) * 8;   // phys slot*8 for all fragment reads

  // prologue: stage K-tile 0 only (A0,B0,A1,B1) — 8 loads/thread in flight
  stageHalf(0, 0, 0); stageHalf(0, 0, 1); stageHalf(0, 0, 2); stageHalf(0, 0, 3);

  for (int kt = 0; kt < NT; ++kt) {
    const int bf = kt & 1;
    const bool st = (kt + 1 < NT);
#pragma unroll
    for (int ph = 0; ph < 4; ++ph) {
      const int sub = ph >> 1, mh = ph & 1;
      if (ph == 0) {
        asm volatile("s_waitcnt vmcnt(4)" ::: "memory");
      } else if (ph == 2) {
        if (kt == NT - 1) asm volatile("s_waitcnt vmcnt(0)" ::: "memory");
        else              asm volatile("s_waitcnt vmcnt(4)" ::: "memory");
      } else {
        asm volatile("s_waitcnt vmcnt(6)" ::: "memory");
      }
      __builtin_amdgcn_s_barrier();        // all waves: required halves landed, prev reads done
      if (mh == 0) {
#pragma unroll
        for (int ni = 0; ni < 4; ++ni)
          bfr[ni] = *reinterpret_cast<const bf16x8*>(&Bs[bf][sub][wn*64 + ni*16 + lr][sp]);
      }
#pragma unroll
      for (int i = 0; i < 4; ++i)
        afr[i] = *reinterpret_cast<const bf16x8*>(&As[bf][sub][wm*128 + (mh*4 + i)*16 + lr][sp]);
      if (st) stageHalf(bf ^ 1, kt + 1, ph);
      asm volatile("s_waitcnt lgkmcnt(0)" ::: "memory");
      __builtin_amdgcn_sched_barrier(0);
      __builtin_amdgcn_s_setprio(1);
#pragma unroll
      for (int i = 0; i < 4; ++i)
#pragma unroll
        for (int ni = 0; ni < 4; ++ni)     // swapped -> C^T fragment layout
          acc[mh*4 + i][ni] =
              __builtin_amdgcn_mfma_f32_16x16x32_bf16(bfr[ni], afr[i], acc[mh*4 + i][ni], 0, 0, 0);
      __builtin_amdgcn_s_setprio(0);
    }
  }

  // epilogue: row = lane&15, cols = (lane>>4)*4 .. +3
  const int cq = sl * 4;
#pragma unroll
  for (int mi = 0; mi < 8; ++mi) {
    const int r = wm*128 + mi*16 + lr;
    if (bx*256 + r < rowsValid) {
      const long grow = rowBase + r;
#pragma unroll
      for (int ni = 0; ni < 4; ++ni) {
        const int c0 = colBase + wn*64 + ni*16 + cq;
        const long oidx = grow*(long)ldo + c0;
        f32x4 v = acc[mi][ni] + *reinterpret_cast<const f32x4*>(&biasP[c0]);
        if (EPI == 0) {
          uint2 pk; pk.x = cvt_pk_bf16(v[0], v[1]); pk.y = cvt_pk_bf16(v[2], v[3]);
          *reinterpret_cast<uint2*>((u16*)outp + oidx) = pk;
        } else if (EPI == 1) {
          uint2 pk; pk.x = cvt_pk_bf16(gelu_f(v[0]), gelu_f(v[1]));
          pk.y = cvt_pk_bf16(gelu_f(v[2]), gelu_f(v[3]));
          *reinterpret_cast<uint2*>((u16*)outp + oidx) = pk;
        } else {
          f32x4 rv = *reinterpret_cast<const f32x4*>((const float*)res + oidx);
          *reinterpret_cast<f32x4*>((float*)outp + oidx) = v + rv;
        }
      }
    }
  }
}

// ---------------- LayerNorm over C=256, one wave per token, bf16 out ----------------
__global__ __launch_bounds__(256)
void ln_kernel(const float* __restrict__ in, const float* __restrict__ g,
               const float* __restrict__ bt, u16* __restrict__ out, int M)
{
  const int wv = threadIdx.x >> 6, lane = threadIdx.x & 63;
  const int t = blockIdx.x * 4 + wv;
  if (t >= M) return;
  const float4 x = reinterpret_cast<const float4*>(in + (long)t*256)[lane];
  float s = x.x + x.y + x.z + x.w;
  float q = x.x*x.x + x.y*x.y + x.z*x.z + x.w*x.w;
#pragma unroll
  for (int o = 32; o > 0; o >>= 1) { s += __shfl_xor(s, o); q += __shfl_xor(q, o); }
  const float m  = s * (1.0f/256.0f);
  const float var = q * (1.0f/256.0f) - m*m;
  const float rs = rsqrtf(var + 1e-5f);
  const float4 gv = reinterpret_cast<const float4*>(g)[lane];
  const float4 bv = reinterpret_cast<const float4*>(bt)[lane];
  uint2 o4;
  o4.x = cvt_pk_bf16((x.x - m)*rs*gv.x + bv.x, (x.y - m)*rs*gv.y + bv.y);
  o4.y = cvt_pk_bf16((x.z - m)*rs*gv.z + bv.z, (x.w - m)*rs*gv.w + bv.w);
  *reinterpret_cast<uint2*>(out + (long)t*256 + lane*4) = o4;
}

// -------- fused per-head LN(k), LN(v) + kv[b,h] += k^T v / N (atomic f32) --------
// KV buffer layout: [M][512] = [k(256) | v(256)]
__global__ __launch_bounds__(256)
void kv_kernel(const u16* __restrict__ KV,
               const float* __restrict__ kg, const float* __restrict__ kb,
               const float* __restrict__ vg, const float* __restrict__ vb,
               float* __restrict__ kvout)
{
  const int bh = blockIdx.x, b = bh >> 3, h = bh & 7;
  const int tid = threadIdx.x;
  __shared__ u16 kls[256][32];
  __shared__ u16 vls[256][32];
  __shared__ float sg[4][32];
  if (tid < 32) {
    sg[0][tid] = kg[h*32 + tid];
    sg[1][tid] = kb[h*32 + tid];
    sg[2][tid] = vg[h*32 + tid];
    sg[3][tid] = vb[h*32 + tid];
  }
  const int d = tid >> 3, e0 = (tid & 7) * 4;
  float a0=0, a1=0, a2=0, a3=0;

  for (int sub = 0; sub < 2; ++sub) {
    const int r = blockIdx.y * 512 + sub * 256 + tid;
    __syncthreads();
    if (r < NTOK) {
      const u16* rowp = KV + (long)(b*NTOK + r)*512;
#pragma unroll
      for (int kv2 = 0; kv2 < 2; ++kv2) {
        const u16* p = rowp + (kv2 ? 256 : 0) + h*32;
        float xv[32]; float s = 0.f;
#pragma unroll
        for (int q4 = 0; q4 < 4; ++q4) {
          u16x8 u = *reinterpret_cast<const u16x8*>(p + q4*8);
#pragma unroll
          for (int j = 0; j < 8; ++j) { float f = bf2f(u[j]); xv[q4*8+j] = f; s += f; }
        }
        const float m = s * (1.0f/32.0f);
        float vv = 0.f;
#pragma unroll
        for (int j = 0; j < 32; ++j) { float d2 = xv[j]-m; vv += d2*d2; }
        const float rs = rsqrtf(vv*(1.0f/32.0f) + 1e-5f);
        const float* gg = sg[kv2 ? 2 : 0];
        const float* bb = sg[kv2 ? 3 : 1];
        u16 (*dst)[32] = kv2 ? vls : kls;
#pragma unroll
        for (int j = 0; j < 32; ++j) dst[tid][j] = f2bf((xv[j]-m)*rs*gg[j] + bb[j]);
      }
    } else {
#pragma unroll
      for (int j = 0; j < 32; ++j) { kls[tid][j] = 0; vls[tid][j] = 0; }
    }
    __syncthreads();
#pragma unroll 4
    for (int rr = 0; rr < 256; ++rr) {
      const float kd = bf2f(kls[rr][d]);
      u16x4 v4 = *reinterpret_cast<const u16x4*>(&vls[rr][e0]);
      a0 += kd * bf2f(v4[0]); a1 += kd * bf2f(v4[1]);
      a2 += kd * bf2f(v4[2]); a3 += kd * bf2f(v4[3]);
    }
  }
  const float sc = 1.0f / (float)NTOK;
  float* o = kvout + (long)bh*1024 + d*32 + e0;
  atomicAdd(o+0, a0*sc); atomicAdd(o+1, a1*sc);
  atomicAdd(o+2, a2*sc); atomicAdd(o+3, a3*sc);
}

// -------- Woe_t[b][c][j=h*32+d] = sum_e kv[b,h,d,e] * Wo[h*32+e][c]  (= kvWo[j][c], bf16) ----
__global__ __launch_bounds__(256)
void woeff_kernel(const float* __restrict__ kv, const float* __restrict__ Wo,
                  u16* __restrict__ Woet)
{
  const int b = blockIdx.x >> 8, c = blockIdx.x & 255;
  const int rtid = threadIdx.x;
  const int h = rtid >> 5, dd = rtid & 31;
  const float* kvp = kv + ((long)(b*8 + h)*32 + dd)*32;
  float s = 0.f;
#pragma unroll 8
  for (int e = 0; e < 32; ++e) s += kvp[e] * Wo[(h*32 + e)*256 + c];
  Woet[(long)(b*256 + c)*256 + rtid] = f2bf(s);
}

// -------- Watt[b][c][k] = sum_j Wq[k,j] * kvWo[b][j,c]  (B^T layout for att GEMM) --------
__global__ __launch_bounds__(256)
void watt_kernel(const u16* __restrict__ wq_bf, const u16* __restrict__ Woet,
                 u16* __restrict__ Watt)
{
  const int b = blockIdx.x >> 8, c = blockIdx.x & 255;
  const int k = threadIdx.x;
  const u16* wr = wq_bf + (long)k*256;
  const u16* er = Woet + ((long)(b*256 + c))*256;
  float s = 0.f;
#pragma unroll 4
  for (int j0 = 0; j0 < 256; j0 += 8) {
    u16x8 wv = *reinterpret_cast<const u16x8*>(wr + j0);
    u16x8 ev = *reinterpret_cast<const u16x8*>(er + j0);
#pragma unroll
    for (int j = 0; j < 8; ++j) s += bf2f(wv[j]) * bf2f(ev[j]);
  }
  Watt[((long)(b*256 + c))*256 + k] = f2bf(s);
}

// -------- be[b][c] = sum_j bq[j] * kvWo[b][j,c] + bo[c] --------
__global__ __launch_bounds__(256)
void be_kernel(const float* __restrict__ bq, const float* __restrict__ bo,
               const u16* __restrict__ Woet, float* __restrict__ be)
{
  const int b = blockIdx.x, c = threadIdx.x;
  const u16* er = Woet + ((long)(b*256 + c))*256;
  float s = bo[c];
#pragma unroll 4
  for (int j0 = 0; j0 < 256; j0 += 8) {
    u16x8 ev = *reinterpret_cast<const u16x8*>(er + j0);
#pragma unroll
    for (int j = 0; j < 8; ++j) s += bq[j0+j] * bf2f(ev[j]);
  }
  be[b*256 + c] = s;
}

// ---------------- prep kernels ----------------
__global__ void zero_f32(float* p, int n) {
  int i = blockIdx.x*blockDim.x + threadIdx.x; if (i < n) p[i] = 0.f;
}
__global__ void concat_bias2(const float* bk, const float* bv, float* o) {
  int i = threadIdx.x;
  o[i] = (i < 256) ? bk[i] : bv[i-256];
}
__global__ void cvt_bf(const float* __restrict__ src, u16* __restrict__ dst, int n) {
  int i = blockIdx.x*blockDim.x + threadIdx.x; if (i < n) dst[i] = f2bf(src[i]);
}
__global__ __launch_bounds__(256)
void transpose_cvt(const float* __restrict__ src, u16* __restrict__ dst, int R, int C) {
  __shared__ float t[32][33];
  const int tc = blockIdx.x * 32, tr = blockIdx.y * 32;
  const int lx = threadIdx.x & 31, ly = threadIdx.x >> 5;
#pragma unroll
  for (int i = 0; i < 32; i += 8)
    t[ly + i][lx] = src[(long)(tr + ly + i)*C + tc + lx];
  __syncthreads();
#pragma unroll
  for (int i = 0; i < 32; i += 8)
    dst[(long)(tc + ly + i)*R + tr + lx] = f2bf(t[lx][ly + i]);
}

// ---------------- launch ----------------
extern "C" void kernel_launch(void* const* d_in, const int* in_sizes, int n_in,
                              void* d_out, int out_size, void* d_ws, size_t ws_size,
                              hipStream_t stream)
{
  const float* fx    = (const float*)d_in[0];
  const float* ln1_g = (const float*)d_in[1];
  const float* ln1_b = (const float*)d_in[2];
  const float* Wq = (const float*)d_in[3];
  const float* bq = (const float*)d_in[4];
  const float* Wk = (const float*)d_in[5];
  const float* bk = (const float*)d_in[6];
  const float* Wv = (const float*)d_in[7];
  const float* bv = (const float*)d_in[8];
  const float* Wo = (const float*)d_in[9];
  const float* bo = (const float*)d_in[10];
  const float* kg  = (const float*)d_in[11];
  const float* kbb = (const float*)d_in[12];
  const float* vg  = (const float*)d_in[13];
  const float* vbb = (const float*)d_in[14];
  const float* ln2_g = (const float*)d_in[15];
  const float* ln2_b = (const float*)d_in[16];
  const float* W1 = (const float*)d_in[17];
  const float* b1 = (const float*)d_in[18];
  const float* W2 = (const float*)d_in[19];
  const float* b2 = (const float*)d_in[20];
  float* outF = (float*)d_out;

  char* ws = (char*)d_ws;
  size_t off = 0;
  auto alloc = [&](size_t bytes) { char* p = ws + off; off += (bytes + 255) & ~(size_t)255; return p; };
  u16* bufX   = (u16*)alloc((size_t)MROWS*256*2);   // LN1 out, later LN2 out
  u16* bufKV  = (u16*)alloc((size_t)MROWS*512*2);
  u16* bufH   = (u16*)alloc((size_t)MROWS*1024*2);
  u16* Wkv_t  = (u16*)alloc(512*256*2);
  u16* W1_t   = (u16*)alloc(1024*256*2);
  u16* W2_t   = (u16*)alloc(256*1024*2);
  u16* Woe_t  = (u16*)alloc((size_t)8*256*256*2);
  u16* Watt   = (u16*)alloc((size_t)8*256*256*2);
  u16* wq_bf  = (u16*)alloc(256*256*2);
  float* kvb  = (float*)alloc((size_t)64*1024*4);
  float* bkv  = (float*)alloc(512*4);
  float* be   = (float*)alloc(8*256*4);
  (void)ws_size; (void)out_size; (void)n_in; (void)in_sizes;

  // prep
  zero_f32<<<256, 256, 0, stream>>>(kvb, 65536);
  concat_bias2<<<1, 512, 0, stream>>>(bk, bv, bkv);
  cvt_bf<<<256, 256, 0, stream>>>(Wq, wq_bf, 65536);
  transpose_cvt<<<dim3(8,8),  256, 0, stream>>>(Wk, Wkv_t,         256, 256);
  transpose_cvt<<<dim3(8,8),  256, 0, stream>>>(Wv, Wkv_t + 65536, 256, 256);
  transpose_cvt<<<dim3(32,8), 256, 0, stream>>>(W1, W1_t, 256, 1024);
  transpose_cvt<<<dim3(8,32), 256, 0, stream>>>(W2, W2_t, 1024, 256);

  // x = LN1(fx)
  ln_kernel<<<MTOT/4, 256, 0, stream>>>(fx, ln1_g, ln1_b, bufX, MTOT);

  // KV = x @ [Wk|Wv] + [bk|bv] : M-tiles 226, N-tiles 2, K=256
  gemm256<0><<<dim3(MT_FULL, 2, 1), 512, 0, stream>>>(
      bufX, 256, Wkv_t, 256, 0, bkv, 0, nullptr, bufKV, 512, 256, MTOT, 0);

  // kv[b,h] = LN(k)^T LN(v) / N
  kv_kernel<<<dim3(64, 15), 256, 0, stream>>>(bufKV, kg, kbb, vg, vbb, kvb);

  // kvWo, W_att, be
  woeff_kernel<<<2048, 256, 0, stream>>>(kvb, Wo, Woe_t);
  watt_kernel<<<2048, 256, 0, stream>>>(wq_bf, Woe_t, Watt);
  be_kernel<<<8, 256, 0, stream>>>(bq, bo, Woe_t, be);

  // out = fx + x @ W_att[b] + be[b] : per-batch M-tiles 29, N-tiles 1, K=256
  gemm256<2><<<dim3(MT_BATCH, 1, 8), 512, 0, stream>>>(
      bufX, 256, Watt, 256, 65536, be, 256, fx, outF, 256, 256, NTOK, NTOK);

  // x2 = LN2(out)
  ln_kernel<<<MTOT/4, 256, 0, stream>>>(outF, ln2_g, ln2_b, bufX, MTOT);

  // H = gelu(x2 @ W1 + b1) : N-tiles 4, K=256
  gemm256<1><<<dim3(MT_FULL, 4, 1), 512, 0, stream>>>(
      bufX, 256, W1_t, 256, 0, b1, 0, nullptr, bufH, 1024, 256, MTOT, 0);

  // out = out + H @ W2 + b2 : N-tiles 1, K=1024
  gemm256<2><<<dim3(MT_FULL, 1, 1), 512, 0, stream>>>(
      bufH, 1024, W2_t, 1024, 0, b2, 0, outF, outF, 256, 1024, MTOT, 0);
}

// Round 8
// 350.011 us; speedup vs baseline: 1.1173x; 1.0180x over previous
//
#include <hip/hip_runtime.h>
#include <hip/hip_bf16.h>
#include <stdint.h>

#define B_ 8
#define NTOK 7225
#define MTOT (B_*NTOK)      // 57800
#define MROWS 58368         // padded rows for all M-row buffers (228*256)
#define MT_FULL 226         // ceil(57800/256)
#define MT_BATCH 29         // ceil(7225/256)

typedef unsigned short u16;
typedef u16 u16x8 __attribute__((ext_vector_type(8)));
typedef u16 u16x4 __attribute__((ext_vector_type(4)));
typedef __bf16 bf16x8 __attribute__((ext_vector_type(8)));
typedef float f32x4 __attribute__((ext_vector_type(4)));

__device__ inline float bf2f(u16 u){ union{float f;uint32_t i;}c; c.i=((uint32_t)u)<<16; return c.f; }
__device__ inline u16 f2bf(float f){ union{float f;uint32_t i;}c; c.f=f; uint32_t x=c.i;
                                     return (u16)((x + 0x7fffu + ((x>>16)&1u))>>16); }
__device__ inline uint32_t cvt_pk_bf16(float a, float b){
  uint32_t r; asm("v_cvt_pk_bf16_f32 %0, %1, %2" : "=v"(r) : "v"(a), "v"(b)); return r;
}
// fast tanh-gelu: 0.5x(1+tanh t) == x * (1 - 1/(exp(2t)+1))
__device__ inline float gelu_f(float x){
  float t = 0.7978845608028654f * x * (1.0f + 0.044715f*x*x);
  float e = __expf(2.0f*t);
  return x * (1.0f - __builtin_amdgcn_rcpf(e + 1.0f));
}

__device__ inline void gload_lds16(const u16* g, u16* l) {
  __builtin_amdgcn_global_load_lds(
      (__attribute__((address_space(1))) void*)(const_cast<u16*>(g)),
      (__attribute__((address_space(3))) void*)(l), 16, 0, 0);
}

// ============ 256x256-tile GEMM, m201-ordered phases (reads BEFORE barrier) ============
// C[M,N] = A[M,K](bf16) * B^T-layout[N,K](bf16) + epilogue
//   EPI 0: bf16 = acc+bias   EPI 1: bf16 = gelu(acc+bias)   EPI 2: f32 = acc+bias+res
//   EPI 3: f32 out = v = acc+bias+res  AND  bf16 x2 = LayerNorm_row(v)*g2+b2  (fused LN2)
// 512 threads = 8 waves (2M x 4N), wave tile 128x64. K-tile BK=64, halves A0,B0,A1,B1
// ([256][32] u16, 64B rows, measured-zero-conflict swizzle phys_slot = slot ^ ((row>>1)&3),
// pre-applied on the GLOBAL col; LDS dest linear per G21). 4 phases per K-tile.
//
// Phase body (m201 order):
//   [ds_read frags of half(ph)]  [stage half(ph) of kt+1]  [vmcnt publication at ph1/ph3]
//   -> s_barrier -> lgkmcnt(0)+sched_barrier -> setprio(1) 16 MFMA setprio(0) -> s_barrier
// Publication invariant: vmcnt(4) immediately before the mid-barrier at ph1 (publishes this
// tile's A1,B1) and ph3 (publishes next tile's A0,B0); after that barrier ALL waves' loads
// older than the newest 4 are visible, so reads-before-barrier in later phases are safe.
// Last tile: ph1 uses vmcnt(0) (drain), ph3 skips (nothing pending).
// MFMA swapped: mfma(b, a, acc) -> C^T fragment: row = lane&15, col = (lane>>4)*4 + reg.
template<int EPI>
__global__ __launch_bounds__(512, 2)
void gemm256(const u16* __restrict__ A, int lda,
             const u16* __restrict__ Bm, int ldb, long bStride,
             const float* __restrict__ bias, int biasStride,
             const float* __restrict__ res,
             void* __restrict__ outp, int ldo,
             int K, int rowsValid, int batchRowStride,
             const float* __restrict__ g2, const float* __restrict__ b2,
             u16* __restrict__ x2out)
{
  __shared__ alignas(16) u16 As[2][2][256][32];
  __shared__ alignas(16) u16 Bs[2][2][256][32];
  const int tid = threadIdx.x;
  const int wid = tid >> 6, lane = tid & 63;
  const int wm = wid >> 2, wn = wid & 3;

  // bijective XCD swizzle (m204) over x,y
  const int gx = gridDim.x, gy = gridDim.y;
  const int n = gx * gy;
  const int flat = blockIdx.y * gx + blockIdx.x;
  const int qq = n >> 3, rr = n & 7;
  const int xcd = flat & 7, pos = flat >> 3;
  const int swz = (xcd < rr ? xcd*(qq+1) : rr*(qq+1) + (xcd-rr)*qq) + pos;
  const int bx = swz / gy, by = swz % gy;
  const int bz = blockIdx.z;

  const long rowBase = (long)bz * batchRowStride + (long)bx * 256;
  const int colBase = by * 256;
  const u16* Bp = Bm + (long)bz * bStride;
  const float* biasP = bias + bz * biasStride;

  const int srow = lane >> 2;                              // 0..15
  const int scol = ((lane & 3) ^ ((lane >> 3) & 3)) * 8;   // pre-swizzled global slot
  const int NT = K >> 6;

  // stage one 16KB half-tile: sel 0=A-sub0 1=B-sub0 2=A-sub1 3=B-sub1
  auto stageHalf = [&](int bf, int kt, int sel) {
    const int sub = sel >> 1;
    const int k0 = (kt << 6) + sub*32 + scol;
#pragma unroll
    for (int i = 0; i < 2; ++i) {
      const int r0 = (wid*2 + i)*16;
      if ((sel & 1) == 0)
        gload_lds16(A + (rowBase + r0 + srow)*(long)lda + k0, &As[bf][sub][r0][0]);
      else
        gload_lds16(Bp + (long)(colBase + r0 + srow)*ldb + k0, &Bs[bf][sub][r0][0]);
    }
  };

  f32x4 acc[8][4] = {};
  bf16x8 afr[4], bfr[4];
  const int lr = lane & 15;
  const int sl = lane >> 4;
  const int sp = (sl ^ ((lr >> 1) & 3)) * 8;   // phys slot*8 for all fragment reads

  // prologue: stage K-tile 0 (A0,B0,A1,B1), publish A0,B0
  stageHalf(0, 0, 0); stageHalf(0, 0, 1); stageHalf(0, 0, 2); stageHalf(0, 0, 3);
  asm volatile("s_waitcnt vmcnt(4)" ::: "memory");
  __builtin_amdgcn_s_barrier();

  for (int kt = 0; kt < NT; ++kt) {
    const int bf = kt & 1;
    const bool st = (kt + 1 < NT);
#pragma unroll
    for (int ph = 0; ph < 4; ++ph) {
      const int sub = ph >> 1, mh = ph & 1;
      // --- reads first (latency hides under barrier + others' MFMA tails)
      if (mh == 0) {
#pragma unroll
        for (int ni = 0; ni < 4; ++ni)
          bfr[ni] = *reinterpret_cast<const bf16x8*>(&Bs[bf][sub][wn*64 + ni*16 + lr][sp]);
      }
#pragma unroll
      for (int i = 0; i < 4; ++i)
        afr[i] = *reinterpret_cast<const bf16x8*>(&As[bf][sub][wm*128 + (mh*4 + i)*16 + lr][sp]);
      // --- stage next tile's matching half
      if (st) stageHalf(bf ^ 1, kt + 1, ph);
      // --- vmcnt publication points (immediately before the barrier)
      if (ph == 1) {
        if (st) asm volatile("s_waitcnt vmcnt(4)" ::: "memory");
        else    asm volatile("s_waitcnt vmcnt(0)" ::: "memory");
      } else if (ph == 3) {
        if (st) asm volatile("s_waitcnt vmcnt(4)" ::: "memory");
      }
      __builtin_amdgcn_sched_barrier(0);
      __builtin_amdgcn_s_barrier();
      asm volatile("s_waitcnt lgkmcnt(0)" ::: "memory");
      __builtin_amdgcn_sched_barrier(0);
      __builtin_amdgcn_s_setprio(1);
#pragma unroll
      for (int i = 0; i < 4; ++i)
#pragma unroll
        for (int ni = 0; ni < 4; ++ni)     // swapped -> C^T fragment layout
          acc[mh*4 + i][ni] =
              __builtin_amdgcn_mfma_f32_16x16x32_bf16(bfr[ni], afr[i], acc[mh*4 + i][ni], 0, 0, 0);
      __builtin_amdgcn_s_setprio(0);
      __builtin_amdgcn_s_barrier();
    }
  }

  // ---------------- epilogue: row = lane&15, cols = (lane>>4)*4 .. +3 ----------------
  const int cq = sl * 4;
  if (EPI != 3) {
#pragma unroll
    for (int mi = 0; mi < 8; ++mi) {
      const int r = wm*128 + mi*16 + lr;
      if (bx*256 + r < rowsValid) {
        const long grow = rowBase + r;
#pragma unroll
        for (int ni = 0; ni < 4; ++ni) {
          const int c0 = colBase + wn*64 + ni*16 + cq;
          const long oidx = grow*(long)ldo + c0;
          f32x4 v = acc[mi][ni] + *reinterpret_cast<const f32x4*>(&biasP[c0]);
          if (EPI == 0) {
            uint2 pk; pk.x = cvt_pk_bf16(v[0], v[1]); pk.y = cvt_pk_bf16(v[2], v[3]);
            *reinterpret_cast<uint2*>((u16*)outp + oidx) = pk;
          } else if (EPI == 1) {
            uint2 pk; pk.x = cvt_pk_bf16(gelu_f(v[0]), gelu_f(v[1]));
            pk.y = cvt_pk_bf16(gelu_f(v[2]), gelu_f(v[3]));
            *reinterpret_cast<uint2*>((u16*)outp + oidx) = pk;
          } else {
            f32x4 rv = *reinterpret_cast<const f32x4*>((const float*)res + oidx);
            *reinterpret_cast<f32x4*>((float*)outp + oidx) = v + rv;
          }
        }
      }
    }
  } else {
    // EPI 3: v = acc + be + fx (residual); out=v (f32); x2 = LN_row(v)*g2+b2 (bf16).
    // Block covers full C=256 (colBase==0, ldo==256). Row r's cols live in lanes
    // {lr, lr+16, lr+32, lr+48} of the 4 wn-waves (same wm). Reduce: lane-local ->
    // shfl_xor(16,32) -> LDS across wn -> normalize.
    float* red = reinterpret_cast<float*>(&As[0][0][0][0]);   // [2 arrays][8 slots][128 rows]
    // pass 1: v into acc, per-row partial stats
#pragma unroll
    for (int mi = 0; mi < 8; ++mi) {
      const int r = wm*128 + mi*16 + lr;
      const bool valid = (bx*256 + r < rowsValid);
      const long grow = rowBase + r;
      float s_r = 0.f, q_r = 0.f;
#pragma unroll
      for (int ni = 0; ni < 4; ++ni) {
        const int c0 = wn*64 + ni*16 + cq;
        f32x4 rv = valid ? *reinterpret_cast<const f32x4*>((const float*)res + grow*256 + c0)
                         : f32x4{0.f,0.f,0.f,0.f};
        f32x4 v = acc[mi][ni] + *reinterpret_cast<const f32x4*>(&biasP[c0]) + rv;
        acc[mi][ni] = v;
        s_r += v[0]+v[1]+v[2]+v[3];
        q_r += v[0]*v[0]+v[1]*v[1]+v[2]*v[2]+v[3]*v[3];
      }
      s_r += __shfl_xor(s_r, 16); s_r += __shfl_xor(s_r, 32);
      q_r += __shfl_xor(q_r, 16); q_r += __shfl_xor(q_r, 32);
      if (sl == 0) {
        red[       (wm*4 + wn)*128 + mi*16 + lr] = s_r;
        red[1024 + (wm*4 + wn)*128 + mi*16 + lr] = q_r;
      }
    }
    __syncthreads();
    // pass 2: normalize + store out f32 and x2 bf16
#pragma unroll
    for (int mi = 0; mi < 8; ++mi) {
      const int r = wm*128 + mi*16 + lr;
      if (bx*256 + r >= rowsValid) continue;
      const long grow = rowBase + r;
      const int rb = wm*4*128 + mi*16 + lr;
      float s_t = red[rb] + red[rb+128] + red[rb+256] + red[rb+384];
      float q_t = red[1024+rb] + red[1024+rb+128] + red[1024+rb+256] + red[1024+rb+384];
      const float m = s_t * (1.0f/256.0f);
      const float var = q_t * (1.0f/256.0f) - m*m;
      const float rs = rsqrtf(var + 1e-5f);
#pragma unroll
      for (int ni = 0; ni < 4; ++ni) {
        const int c0 = wn*64 + ni*16 + cq;
        const long oidx = grow*256 + c0;
        f32x4 v = acc[mi][ni];
        *reinterpret_cast<f32x4*>((float*)outp + oidx) = v;
        f32x4 gv = *reinterpret_cast<const f32x4*>(&g2[c0]);
        f32x4 bv = *reinterpret_cast<const f32x4*>(&b2[c0]);
        f32x4 xn = (v - m) * rs * gv + bv;
        uint2 pk; pk.x = cvt_pk_bf16(xn[0], xn[1]); pk.y = cvt_pk_bf16(xn[2], xn[3]);
        *reinterpret_cast<uint2*>(x2out + oidx) = pk;
      }
    }
  }
}

// ---------------- LayerNorm over C=256, one wave per token, bf16 out ----------------
__global__ __launch_bounds__(256)
void ln_kernel(const float* __restrict__ in, const float* __restrict__ g,
               const float* __restrict__ bt, u16* __restrict__ out, int M)
{
  const int wv = threadIdx.x >> 6, lane = threadIdx.x & 63;
  const int t = blockIdx.x * 4 + wv;
  if (t >= M) return;
  const float4 x = reinterpret_cast<const float4*>(in + (long)t*256)[lane];
  float s = x.x + x.y + x.z + x.w;
  float q = x.x*x.x + x.y*x.y + x.z*x.z + x.w*x.w;
#pragma unroll
  for (int o = 32; o > 0; o >>= 1) { s += __shfl_xor(s, o); q += __shfl_xor(q, o); }
  const float m  = s * (1.0f/256.0f);
  const float var = q * (1.0f/256.0f) - m*m;
  const float rs = rsqrtf(var + 1e-5f);
  const float4 gv = reinterpret_cast<const float4*>(g)[lane];
  const float4 bv = reinterpret_cast<const float4*>(bt)[lane];
  uint2 o4;
  o4.x = cvt_pk_bf16((x.x - m)*rs*gv.x + bv.x, (x.y - m)*rs*gv.y + bv.y);
  o4.y = cvt_pk_bf16((x.z - m)*rs*gv.z + bv.z, (x.w - m)*rs*gv.w + bv.w);
  *reinterpret_cast<uint2*>(out + (long)t*256 + lane*4) = o4;
}

// -------- fused per-head LN(k), LN(v) + kv[b,h] += k^T v / N (atomic f32) --------
// KV buffer layout: [M][512] = [k(256) | v(256)]
__global__ __launch_bounds__(256)
void kv_kernel(const u16* __restrict__ KV,
               const float* __restrict__ kg, const float* __restrict__ kb,
               const float* __restrict__ vg, const float* __restrict__ vb,
               float* __restrict__ kvout)
{
  const int bh = blockIdx.x, b = bh >> 3, h = bh & 7;
  const int tid = threadIdx.x;
  __shared__ u16 kls[256][32];
  __shared__ u16 vls[256][32];
  __shared__ float sg[4][32];
  if (tid < 32) {
    sg[0][tid] = kg[h*32 + tid];
    sg[1][tid] = kb[h*32 + tid];
    sg[2][tid] = vg[h*32 + tid];
    sg[3][tid] = vb[h*32 + tid];
  }
  const int d = tid >> 3, e0 = (tid & 7) * 4;
  float a0=0, a1=0, a2=0, a3=0;

  for (int sub = 0; sub < 2; ++sub) {
    const int r = blockIdx.y * 512 + sub * 256 + tid;
    __syncthreads();
    if (r < NTOK) {
      const u16* rowp = KV + (long)(b*NTOK + r)*512;
#pragma unroll
      for (int kv2 = 0; kv2 < 2; ++kv2) {
        const u16* p = rowp + (kv2 ? 256 : 0) + h*32;
        float xv[32]; float s = 0.f;
#pragma unroll
        for (int q4 = 0; q4 < 4; ++q4) {
          u16x8 u = *reinterpret_cast<const u16x8*>(p + q4*8);
#pragma unroll
          for (int j = 0; j < 8; ++j) { float f = bf2f(u[j]); xv[q4*8+j] = f; s += f; }
        }
        const float m = s * (1.0f/32.0f);
        float vv = 0.f;
#pragma unroll
        for (int j = 0; j < 32; ++j) { float d2 = xv[j]-m; vv += d2*d2; }
        const float rs = rsqrtf(vv*(1.0f/32.0f) + 1e-5f);
        const float* gg = sg[kv2 ? 2 : 0];
        const float* bb = sg[kv2 ? 3 : 1];
        u16 (*dst)[32] = kv2 ? vls : kls;
#pragma unroll
        for (int j = 0; j < 32; ++j) dst[tid][j] = f2bf((xv[j]-m)*rs*gg[j] + bb[j]);
      }
    } else {
#pragma unroll
      for (int j = 0; j < 32; ++j) { kls[tid][j] = 0; vls[tid][j] = 0; }
    }
    __syncthreads();
#pragma unroll 4
    for (int rr = 0; rr < 256; ++rr) {
      const float kd = bf2f(kls[rr][d]);
      u16x4 v4 = *reinterpret_cast<const u16x4*>(&vls[rr][e0]);
      a0 += kd * bf2f(v4[0]); a1 += kd * bf2f(v4[1]);
      a2 += kd * bf2f(v4[2]); a3 += kd * bf2f(v4[3]);
    }
  }
  const float sc = 1.0f / (float)NTOK;
  float* o = kvout + (long)bh*1024 + d*32 + e0;
  atomicAdd(o+0, a0*sc); atomicAdd(o+1, a1*sc);
  atomicAdd(o+2, a2*sc); atomicAdd(o+3, a3*sc);
}

// -------- Woe_t[b][c][j=h*32+d] = sum_e kv[b,h,d,e] * Wo[h*32+e][c]  (= kvWo[j][c], bf16) ----
__global__ __launch_bounds__(256)
void woeff_kernel(const float* __restrict__ kv, const float* __restrict__ Wo,
                  u16* __restrict__ Woet)
{
  const int b = blockIdx.x >> 8, c = blockIdx.x & 255;
  const int rtid = threadIdx.x;
  const int h = rtid >> 5, dd = rtid & 31;
  const float* kvp = kv + ((long)(b*8 + h)*32 + dd)*32;
  float s = 0.f;
#pragma unroll 8
  for (int e = 0; e < 32; ++e) s += kvp[e] * Wo[(h*32 + e)*256 + c];
  Woet[(long)(b*256 + c)*256 + rtid] = f2bf(s);
}

// -------- Watt[b][c][k] = sum_j Wq[k,j] * kvWo[b][j,c]  (B^T layout for att GEMM) --------
__global__ __launch_bounds__(256)
void watt_kernel(const u16* __restrict__ wq_bf, const u16* __restrict__ Woet,
                 u16* __restrict__ Watt)
{
  const int b = blockIdx.x >> 8, c = blockIdx.x & 255;
  const int k = threadIdx.x;
  const u16* wr = wq_bf + (long)k*256;
  const u16* er = Woet + ((long)(b*256 + c))*256;
  float s = 0.f;
#pragma unroll 4
  for (int j0 = 0; j0 < 256; j0 += 8) {
    u16x8 wv = *reinterpret_cast<const u16x8*>(wr + j0);
    u16x8 ev = *reinterpret_cast<const u16x8*>(er + j0);
#pragma unroll
    for (int j = 0; j < 8; ++j) s += bf2f(wv[j]) * bf2f(ev[j]);
  }
  Watt[((long)(b*256 + c))*256 + k] = f2bf(s);
}

// -------- be[b][c] = sum_j bq[j] * kvWo[b][j,c] + bo[c] --------
__global__ __launch_bounds__(256)
void be_kernel(const float* __restrict__ bq, const float* __restrict__ bo,
               const u16* __restrict__ Woet, float* __restrict__ be)
{
  const int b = blockIdx.x, c = threadIdx.x;
  const u16* er = Woet + ((long)(b*256 + c))*256;
  float s = bo[c];
#pragma unroll 4
  for (int j0 = 0; j0 < 256; j0 += 8) {
    u16x8 ev = *reinterpret_cast<const u16x8*>(er + j0);
#pragma unroll
    for (int j = 0; j < 8; ++j) s += bq[j0+j] * bf2f(ev[j]);
  }
  be[b*256 + c] = s;
}

// ---------------- mega-prep: all weight transposes/cvt + bias concat + zero ----------------
__device__ void transpose_tile(const float* __restrict__ src, u16* __restrict__ dst,
                               int R, int C, int tcx, int trY)
{
  __shared__ float t[32][33];
  const int tc = tcx * 32, tr = trY * 32;
  const int lx = threadIdx.x & 31, ly = threadIdx.x >> 5;
#pragma unroll
  for (int i = 0; i < 32; i += 8)
    t[ly + i][lx] = src[(long)(tr + ly + i)*C + tc + lx];
  __syncthreads();
#pragma unroll
  for (int i = 0; i < 32; i += 8)
    dst[(long)(tc + ly + i)*R + tr + lx] = f2bf(t[lx][ly + i]);
}

__global__ __launch_bounds__(256)
void prep_kernel(const float* __restrict__ Wk, const float* __restrict__ Wv,
                 const float* __restrict__ W1, const float* __restrict__ W2,
                 const float* __restrict__ Wq,
                 const float* __restrict__ bk, const float* __restrict__ bv,
                 u16* __restrict__ Wkv_t, u16* __restrict__ W1_t, u16* __restrict__ W2_t,
                 u16* __restrict__ wq_bf, float* __restrict__ kvb, float* __restrict__ bkv)
{
  int b = blockIdx.x;
  if (b < 256)      { transpose_tile(W1, W1_t, 256, 1024, b & 31, b >> 5); }
  else if (b < 512) { b -= 256; transpose_tile(W2, W2_t, 1024, 256, b & 7, b >> 3); }
  else if (b < 576) { b -= 512; transpose_tile(Wk, Wkv_t,         256, 256, b & 7, b >> 3); }
  else if (b < 640) { b -= 576; transpose_tile(Wv, Wkv_t + 65536, 256, 256, b & 7, b >> 3); }
  else if (b < 648) {           // Wq f32 -> bf16 (row-major): 8 blocks x 8192
    const int base = (b - 640) * 8192 + threadIdx.x;
#pragma unroll
    for (int i = 0; i < 32; ++i) wq_bf[base + i*256] = f2bf(Wq[base + i*256]);
  } else if (b < 656) {         // zero kvb: 8 blocks x 8192
    const int base = (b - 648) * 8192 + threadIdx.x;
#pragma unroll
    for (int i = 0; i < 32; ++i) kvb[base + i*256] = 0.f;
  } else {                      // bias concat
    const int i = threadIdx.x;
    bkv[i] = bk[i]; bkv[256 + i] = bv[i];
  }
}

// ---------------- launch ----------------
extern "C" void kernel_launch(void* const* d_in, const int* in_sizes, int n_in,
                              void* d_out, int out_size, void* d_ws, size_t ws_size,
                              hipStream_t stream)
{
  const float* fx    = (const float*)d_in[0];
  const float* ln1_g = (const float*)d_in[1];
  const float* ln1_b = (const float*)d_in[2];
  const float* Wq = (const float*)d_in[3];
  const float* bq = (const float*)d_in[4];
  const float* Wk = (const float*)d_in[5];
  const float* bk = (const float*)d_in[6];
  const float* Wv = (const float*)d_in[7];
  const float* bv = (const float*)d_in[8];
  const float* Wo = (const float*)d_in[9];
  const float* bo = (const float*)d_in[10];
  const float* kg  = (const float*)d_in[11];
  const float* kbb = (const float*)d_in[12];
  const float* vg  = (const float*)d_in[13];
  const float* vbb = (const float*)d_in[14];
  const float* ln2_g = (const float*)d_in[15];
  const float* ln2_b = (const float*)d_in[16];
  const float* W1 = (const float*)d_in[17];
  const float* b1 = (const float*)d_in[18];
  const float* W2 = (const float*)d_in[19];
  const float* b2 = (const float*)d_in[20];
  float* outF = (float*)d_out;

  char* ws = (char*)d_ws;
  size_t off = 0;
  auto alloc = [&](size_t bytes) { char* p = ws + off; off += (bytes + 255) & ~(size_t)255; return p; };
  u16* bufX   = (u16*)alloc((size_t)MROWS*256*2);   // LN1 out, later x2 (LN2 out, fused)
  u16* bufKV  = (u16*)alloc((size_t)MROWS*512*2);
  u16* bufH   = (u16*)alloc((size_t)MROWS*1024*2);
  u16* Wkv_t  = (u16*)alloc(512*256*2);
  u16* W1_t   = (u16*)alloc(1024*256*2);
  u16* W2_t   = (u16*)alloc(256*1024*2);
  u16* Woe_t  = (u16*)alloc((size_t)8*256*256*2);
  u16* Watt   = (u16*)alloc((size_t)8*256*256*2);
  u16* wq_bf  = (u16*)alloc(256*256*2);
  float* kvb  = (float*)alloc((size_t)64*1024*4);
  float* bkv  = (float*)alloc(512*4);
  float* be   = (float*)alloc(8*256*4);
  (void)ws_size; (void)out_size; (void)n_in; (void)in_sizes;

  // prep (single launch)
  prep_kernel<<<657, 256, 0, stream>>>(Wk, Wv, W1, W2, Wq, bk, bv,
                                       Wkv_t, W1_t, W2_t, wq_bf, kvb, bkv);

  // x = LN1(fx)
  ln_kernel<<<MTOT/4, 256, 0, stream>>>(fx, ln1_g, ln1_b, bufX, MTOT);

  // KV = x @ [Wk|Wv] + [bk|bv] : M-tiles 226, N-tiles 2, K=256
  gemm256<0><<<dim3(MT_FULL, 2, 1), 512, 0, stream>>>(
      bufX, 256, Wkv_t, 256, 0, bkv, 0, nullptr, bufKV, 512, 256, MTOT, 0,
      nullptr, nullptr, nullptr);

  // kv[b,h] = LN(k)^T LN(v) / N
  kv_kernel<<<dim3(64, 15), 256, 0, stream>>>(bufKV, kg, kbb, vg, vbb, kvb);

  // kvWo, W_att, be
  woeff_kernel<<<2048, 256, 0, stream>>>(kvb, Wo, Woe_t);
  watt_kernel<<<2048, 256, 0, stream>>>(wq_bf, Woe_t, Watt);
  be_kernel<<<8, 256, 0, stream>>>(bq, bo, Woe_t, be);

  // out = fx + x @ W_att[b] + be[b]  AND  x2 = LN2(out) (fused epilogue, EPI 3)
  gemm256<3><<<dim3(MT_BATCH, 1, 8), 512, 0, stream>>>(
      bufX, 256, Watt, 256, 65536, be, 256, fx, outF, 256, 256, NTOK, NTOK,
      ln2_g, ln2_b, bufX);

  // H = gelu(x2 @ W1 + b1) : N-tiles 4, K=256
  gemm256<1><<<dim3(MT_FULL, 4, 1), 512, 0, stream>>>(
      bufX, 256, W1_t, 256, 0, b1, 0, nullptr, bufH, 1024, 256, MTOT, 0,
      nullptr, nullptr, nullptr);

  // out = out + H @ W2 + b2 : N-tiles 1, K=1024
  gemm256<2><<<dim3(MT_FULL, 1, 1), 512, 0, stream>>>(
      bufH, 1024, W2_t, 1024, 0, b2, 0, outF, outF, 256, 1024, MTOT, 0,
      nullptr, nullptr, nullptr);
}